// Round 10
// baseline (97.627 us; speedup 1.0000x reference)
//
#include <hip/hip_runtime.h>
#include <math.h>

#define BATCH 512    // post-reshape scan lanes
#define FRAGS 256    // fragments per chain
#define GROUP 16     // fragments per scan group == frags per block
#define NGRP  (FRAGS/GROUP)   // 16 groups
#define BTILE 32     // batch lanes per block
#define NTILE (BATCH/BTILE)   // 16 b-tiles
#define RPF   8      // residues per fragment (L=2048)
#define READY 0x5EADBEEF

// Rigid transform: 12 floats, R row-major r[i*3+j], t=[9..11]. x' = Rx + t.
// compose(A,B): A is the EARLIER prefix, B the later. (Verified R5-R9.)
__device__ __forceinline__ void compose(const float* A, const float* B, float* D) {
    float d[12];
    #pragma unroll
    for (int i = 0; i < 3; ++i) {
        #pragma unroll
        for (int j = 0; j < 3; ++j)
            d[i*3+j] = A[i*3+0]*B[0*3+j] + A[i*3+1]*B[1*3+j] + A[i*3+2]*B[2*3+j];
        d[9+i] = A[i*3+0]*B[9] + A[i*3+1]*B[10] + A[i*3+2]*B[11] + A[9+i];
    }
    #pragma unroll
    for (int k = 0; k < 12; ++k) D[k] = d[k];
}

__device__ __forceinline__ void frame_of(
    float ax, float ay, float az,
    float bx, float by, float bz,
    float cx, float cy, float cz,
    float* out /*12*/)
{
    float bcx = cx - bx, bcy = cy - by, bcz = cz - bz;
    float inv = rsqrtf(bcx*bcx + bcy*bcy + bcz*bcz + 1e-12f);
    bcx *= inv; bcy *= inv; bcz *= inv;
    float bax = bx - ax, bay = by - ay, baz = bz - az;
    float nx = bay*bcz - baz*bcy;
    float ny = baz*bcx - bax*bcz;
    float nz = bax*bcy - bay*bcx;
    inv = rsqrtf(nx*nx + ny*ny + nz*nz + 1e-12f);
    nx *= inv; ny *= inv; nz *= inv;
    float mx = ny*bcz - nz*bcy;
    float my = nz*bcx - nx*bcz;
    float mz = nx*bcy - ny*bcx;
    out[0] = bcx; out[1] = mx; out[2] = nx;
    out[3] = bcy; out[4] = my; out[5] = ny;
    out[6] = bcz; out[7] = mz; out[8] = nz;
    out[9] = cx; out[10] = cy; out[11] = cz;
}

__device__ __forceinline__ void nerf_step(
    float ax, float ay, float az,
    float bx, float by, float bz,
    float cx, float cy, float cz,
    float px, float py, float pz,
    float& ox, float& oy, float& oz)
{
    float bcx = cx - bx, bcy = cy - by, bcz = cz - bz;
    float inv = rsqrtf(bcx*bcx + bcy*bcy + bcz*bcz + 1e-12f);
    bcx *= inv; bcy *= inv; bcz *= inv;
    float bax = bx - ax, bay = by - ay, baz = bz - az;
    float nx = bay*bcz - baz*bcy;
    float ny = baz*bcx - bax*bcz;
    float nz = bax*bcy - bay*bcx;
    inv = rsqrtf(nx*nx + ny*ny + nz*nz + 1e-12f);
    nx *= inv; ny *= inv; nz *= inv;
    float mx = ny*bcz - nz*bcy;
    float my = nz*bcx - nx*bcz;
    float mz = nx*bcy - ny*bcx;
    ox = bcx*px + mx*py + nx*pz + cx;
    oy = bcy*px + my*py + ny*pz + cy;
    oz = bcz*px + mz*py + nz*pz + cz;
}

// Per-lane permuted bond constants. Reshape (L,B,3,3)->(3L,B,3) makes scan
// lane b at residue l, step k consume dih flat[l*1536 + 512k + b]; bond-const
// index = (512k+b)%3 -> pattern d = {b%3, (b+2)%3, (b+1)%3}. (Verified R5.)
__device__ __forceinline__ void lane_consts(int b, float* rcl, float* rsl) {
    const float PI = 3.14159265358979323846f;
    float rc[3], rs[3];
    rc[0] = 145.801f * cosf(PI - 2.124f); rs[0] = 145.801f * sinf(PI - 2.124f);
    rc[1] = 152.326f * cosf(PI - 1.941f); rs[1] = 152.326f * sinf(PI - 1.941f);
    rc[2] = 132.868f * cosf(PI - 2.028f); rs[2] = 132.868f * sinf(PI - 2.028f);
    const int d0 = b % 3, d1 = (b + 2) % 3, d2 = (b + 1) % 3;
    rcl[0] = rc[d0]; rcl[1] = rc[d1]; rcl[2] = rc[d2];
    rsl[0] = rs[d0]; rsl[1] = rs[d1]; rsl[2] = rs[d2];
}

// Single-dispatch grid scan via flag lookback (no cooperative launch — R8
// showed hipLaunchCooperativeKernel no-ops under graph capture).
// Block = (g, btile): GROUP frags x BTILE b-lanes. All 256 blocks co-resident
// (1/CU) -> spin-wait cannot deadlock. Flags poisoned 0xAA pre-launch.
//
// R19 theory (I$ streaming): every prior variant was a fully-unrolled
// straight-line kernel (~14-24 KB) executed once per wave — continuous
// instruction-cache miss streaming, which explains the structure-invariant
// ~80%-idle stall floor (VALUBusy 16%, HBM 11%, conflicts 0) that survived
// nine structural attacks. THIS kernel shrinks code ~3x, changing nothing
// else vs R18 (best measured, 92.77): stage-1 / scan / tail become real
// loops (#pragma unroll 1). The register arrays that forced unrolling are
// eliminated via the R13 equivariant-recompute trick (refcheck-passed in
// R4): pass 2 re-walks the chain from the G-transformed init triple and
// emits global points directly, reloading dihedrals (L2-hot, <=1.6MB/XCD).
// Protocol kept from R18: relaxed spin + one acquire fence; j==0-only E_g
// with LDS broadcast.
__global__ void __launch_bounds__(GROUP * BTILE) coord_onepass(
    const float* __restrict__ dih, float* __restrict__ T,
    int* __restrict__ flags, float* __restrict__ out)
{
    const int btile = blockIdx.x & (NTILE - 1);
    const int g     = blockIdx.x >> 4;                 // NTILE==16
    const int bsub  = threadIdx.x & (BTILE - 1);
    const int j     = threadIdx.x >> 5;                // BTILE==32
    const int f     = g * GROUP + j;
    const int b     = btile * BTILE + bsub;

    __shared__ float S[GROUP * BTILE * 13];            // stride 13: conflict-free
    __shared__ float Elds[BTILE * 13];                 // E_g broadcast buffer
    float* Srow = &S[(size_t)threadIdx.x * 13];

    float rcl[3], rsl[3];
    lane_consts(b, rcl, rsl);

    const float IAX = -0.70710678118654752f, IAY = 1.22474487139158905f;
    const float IBX = -1.41421356237309505f;

    // ---- Pass 1: LOOPED local chain; only the end frame is kept ----
    float ax = IAX, ay = IAY, az = 0.0f;
    float bx = IBX, by = 0.0f, bz = 0.0f;
    float cx = 0.0f, cy = 0.0f, cz = 0.0f;

    #pragma unroll 1
    for (int r = 0; r < RPF; ++r) {
        const float* src = dih + (size_t)(f * RPF + r) * (3 * BATCH) + b;
        float d0 = src[0];
        float d1 = src[BATCH];
        float d2 = src[2 * BATCH];
        float sn, cs, ox, oy, oz;
        __sincosf(d0, &sn, &cs);
        nerf_step(ax, ay, az, bx, by, bz, cx, cy, cz,
                  rcl[0], cs * rsl[0], sn * rsl[0], ox, oy, oz);
        ax = bx; ay = by; az = bz; bx = cx; by = cy; bz = cz;
        cx = ox; cy = oy; cz = oz;
        __sincosf(d1, &sn, &cs);
        nerf_step(ax, ay, az, bx, by, bz, cx, cy, cz,
                  rcl[1], cs * rsl[1], sn * rsl[1], ox, oy, oz);
        ax = bx; ay = by; az = bz; bx = cx; by = cy; bz = cz;
        cx = ox; cy = oy; cz = oz;
        __sincosf(d2, &sn, &cs);
        nerf_step(ax, ay, az, bx, by, bz, cx, cy, cz,
                  rcl[2], cs * rsl[2], sn * rsl[2], ox, oy, oz);
        ax = bx; ay = by; az = bz; bx = cx; by = cy; bz = cz;
        cx = ox; cy = oy; cz = oz;
    }

    {
        float h[12];
        frame_of(ax, ay, az, bx, by, bz, cx, cy, cz, h);
        #pragma unroll
        for (int k = 0; k < 12; ++k) Srow[k] = h[k];
    }
    __syncthreads();

    // ---- In-block Hillis-Steele inclusive scan over j (LOOPED rounds) ----
    float tmp[12];
    #pragma unroll 1
    for (int o = 1; o < GROUP; o <<= 1) {
        const bool act = (j >= o);
        if (act) compose(&S[(size_t)(threadIdx.x - o * BTILE) * 13], Srow, tmp);
        __syncthreads();
        if (act) {
            #pragma unroll
            for (int k = 0; k < 12; ++k) Srow[k] = tmp[k];
        }
        __syncthreads();
    }

    // ---- Publish group total T_g (j==GROUP-1 rows), then release flag ----
    if (j == GROUP - 1) {
        #pragma unroll
        for (int k = 0; k < 12; ++k)
            __hip_atomic_store(&T[((size_t)g * 12 + k) * BATCH + b], Srow[k],
                               __ATOMIC_RELAXED, __HIP_MEMORY_SCOPE_AGENT);
    }
    __syncthreads();
    if (threadIdx.x == 0)
        __hip_atomic_store(&flags[g * NTILE + btile], READY,
                           __ATOMIC_RELEASE, __HIP_MEMORY_SCOPE_AGENT);

    // ---- Lookback (R18): relaxed spin, one acquire fence; j==0 row only
    //      computes E_g (serial gp loop), LDS broadcast. ----
    float G[12];
    if (g > 0) {
        if ((int)threadIdx.x < g) {
            while (__hip_atomic_load(&flags[threadIdx.x * NTILE + btile],
                                     __ATOMIC_RELAXED, __HIP_MEMORY_SCOPE_AGENT)
                   != READY) {
                __builtin_amdgcn_s_sleep(1);
            }
        }
        if (j == 0) {
            __builtin_amdgcn_fence(__ATOMIC_ACQUIRE, "agent");
            float E[12];
            #pragma unroll
            for (int k = 0; k < 12; ++k)
                E[k] = __hip_atomic_load(&T[(size_t)k * BATCH + b],
                                         __ATOMIC_RELAXED, __HIP_MEMORY_SCOPE_AGENT);
            #pragma unroll 1
            for (int gp = 1; gp < g; ++gp) {
                float tg[12];
                #pragma unroll
                for (int k = 0; k < 12; ++k)
                    tg[k] = __hip_atomic_load(&T[((size_t)gp * 12 + k) * BATCH + b],
                                              __ATOMIC_RELAXED, __HIP_MEMORY_SCOPE_AGENT);
                compose(E, tg, E);
            }
            #pragma unroll
            for (int k = 0; k < 12; ++k) Elds[bsub * 13 + k] = E[k];
        }
        __syncthreads();
        #pragma unroll
        for (int k = 0; k < 12; ++k) G[k] = Elds[bsub * 13 + k];
    } else {
        G[0]=1.f; G[1]=0.f; G[2]=0.f;
        G[3]=0.f; G[4]=1.f; G[5]=0.f;
        G[6]=0.f; G[7]=0.f; G[8]=1.f;
        G[9]=0.f; G[10]=0.f; G[11]=0.f;
    }
    if (j > 0) {
        // P[f-1] == inclusive prefix row of thread (j-1, bsub), still in LDS.
        compose(G, &S[(size_t)(threadIdx.x - BTILE) * 13], G);
    }

    // ---- Pass 2: LOOPED chain re-walk from the G-transformed init triple
    //      (rigid-motion equivariance, refcheck-passed R4): every emitted
    //      point is already global; store directly. Dihedrals reload from
    //      L2-hot input. ----
    ax = G[0]*IAX + G[1]*IAY + G[9];
    ay = G[3]*IAX + G[4]*IAY + G[10];
    az = G[6]*IAX + G[7]*IAY + G[11];
    bx = G[0]*IBX + G[9];
    by = G[3]*IBX + G[10];
    bz = G[6]*IBX + G[11];
    cx = G[9]; cy = G[10]; cz = G[11];

    #pragma unroll 1
    for (int r = 0; r < RPF; ++r) {
        const float* src = dih + (size_t)(f * RPF + r) * (3 * BATCH) + b;
        float d0 = src[0];
        float d1 = src[BATCH];
        float d2 = src[2 * BATCH];
        float* dst = out + (((size_t)f * (3 * RPF) + r * 3) * BATCH + b) * 3;
        float sn, cs, ox, oy, oz;

        __sincosf(d0, &sn, &cs);
        nerf_step(ax, ay, az, bx, by, bz, cx, cy, cz,
                  rcl[0], cs * rsl[0], sn * rsl[0], ox, oy, oz);
        ax = bx; ay = by; az = bz; bx = cx; by = cy; bz = cz;
        cx = ox; cy = oy; cz = oz;
        dst[0] = ox; dst[1] = oy; dst[2] = oz;

        __sincosf(d1, &sn, &cs);
        nerf_step(ax, ay, az, bx, by, bz, cx, cy, cz,
                  rcl[1], cs * rsl[1], sn * rsl[1], ox, oy, oz);
        ax = bx; ay = by; az = bz; bx = cx; by = cy; bz = cz;
        cx = ox; cy = oy; cz = oz;
        dst += 3 * BATCH;
        dst[0] = ox; dst[1] = oy; dst[2] = oz;

        __sincosf(d2, &sn, &cs);
        nerf_step(ax, ay, az, bx, by, bz, cx, cy, cz,
                  rcl[2], cs * rsl[2], sn * rsl[2], ox, oy, oz);
        ax = bx; ay = by; az = bz; bx = cx; by = cy; bz = cz;
        cx = ox; cy = oy; cz = oz;
        dst += 3 * BATCH;
        dst[0] = ox; dst[1] = oy; dst[2] = oz;
    }
}

extern "C" void kernel_launch(void* const* d_in, const int* in_sizes, int n_in,
                              void* d_out, int out_size, void* d_ws, size_t ws_size,
                              hipStream_t stream) {
    const float* dih = (const float*)d_in[0];
    float* out = (float*)d_out;
    float* T = (float*)d_ws;                           // NGRP*12*BATCH floats
    int* flags = (int*)(T + (size_t)NGRP * 12 * BATCH); // NGRP*NTILE ints

    coord_onepass<<<dim3(NGRP * NTILE), dim3(GROUP * BTILE), 0, stream>>>(
        dih, T, flags, out);
    (void)ws_size; (void)n_in; (void)out_size; (void)in_sizes;
}

// Round 11
// 93.467 us; speedup vs baseline: 1.0445x; 1.0445x over previous
//
#include <hip/hip_runtime.h>
#include <math.h>

#define BATCH 512    // post-reshape scan lanes
#define FRAGS 256    // fragments per chain
#define GROUP 16     // fragments per scan group == frags per block
#define NGRP  (FRAGS/GROUP)   // 16 groups
#define BTILE 32     // batch lanes per block
#define NTILE (BATCH/BTILE)   // 16 b-tiles
#define RPF   8      // residues per fragment (L=2048)

// Rigid transform: 12 floats, R row-major r[i*3+j], t=[9..11]. x' = Rx + t.
// compose(A,B): A is the EARLIER prefix, B the later. (Verified R5-R9.)
__device__ __forceinline__ void compose(const float* A, const float* B, float* D) {
    float d[12];
    #pragma unroll
    for (int i = 0; i < 3; ++i) {
        #pragma unroll
        for (int j = 0; j < 3; ++j)
            d[i*3+j] = A[i*3+0]*B[0*3+j] + A[i*3+1]*B[1*3+j] + A[i*3+2]*B[2*3+j];
        d[9+i] = A[i*3+0]*B[9] + A[i*3+1]*B[10] + A[i*3+2]*B[11] + A[9+i];
    }
    #pragma unroll
    for (int k = 0; k < 12; ++k) D[k] = d[k];
}

__device__ __forceinline__ void frame_of(
    float ax, float ay, float az,
    float bx, float by, float bz,
    float cx, float cy, float cz,
    float* out /*12*/)
{
    float bcx = cx - bx, bcy = cy - by, bcz = cz - bz;
    float inv = rsqrtf(bcx*bcx + bcy*bcy + bcz*bcz + 1e-12f);
    bcx *= inv; bcy *= inv; bcz *= inv;
    float bax = bx - ax, bay = by - ay, baz = bz - az;
    float nx = bay*bcz - baz*bcy;
    float ny = baz*bcx - bax*bcz;
    float nz = bax*bcy - bay*bcx;
    inv = rsqrtf(nx*nx + ny*ny + nz*nz + 1e-12f);
    nx *= inv; ny *= inv; nz *= inv;
    float mx = ny*bcz - nz*bcy;
    float my = nz*bcx - nx*bcz;
    float mz = nx*bcy - ny*bcx;
    out[0] = bcx; out[1] = mx; out[2] = nx;
    out[3] = bcy; out[4] = my; out[5] = ny;
    out[6] = bcz; out[7] = mz; out[8] = nz;
    out[9] = cx; out[10] = cy; out[11] = cz;
}

__device__ __forceinline__ void nerf_step(
    float ax, float ay, float az,
    float bx, float by, float bz,
    float cx, float cy, float cz,
    float px, float py, float pz,
    float& ox, float& oy, float& oz)
{
    float bcx = cx - bx, bcy = cy - by, bcz = cz - bz;
    float inv = rsqrtf(bcx*bcx + bcy*bcy + bcz*bcz + 1e-12f);
    bcx *= inv; bcy *= inv; bcz *= inv;
    float bax = bx - ax, bay = by - ay, baz = bz - az;
    float nx = bay*bcz - baz*bcy;
    float ny = baz*bcx - bax*bcz;
    float nz = bax*bcy - bay*bcx;
    inv = rsqrtf(nx*nx + ny*ny + nz*nz + 1e-12f);
    nx *= inv; ny *= inv; nz *= inv;
    float mx = ny*bcz - nz*bcy;
    float my = nz*bcx - nx*bcz;
    float mz = nx*bcy - ny*bcx;
    ox = bcx*px + mx*py + nx*pz + cx;
    oy = bcy*px + my*py + ny*pz + cy;
    oz = bcz*px + mz*py + nz*pz + cz;
}

// Per-lane permuted bond constants. Reshape (L,B,3,3)->(3L,B,3) makes scan
// lane b at residue l, step k consume dih flat[l*1536 + 512k + b]; bond-const
// index = (512k+b)%3 -> pattern d = {b%3, (b+2)%3, (b+1)%3}. (Verified R5.)
__device__ __forceinline__ void lane_consts(int b, float* rcl, float* rsl) {
    const float PI = 3.14159265358979323846f;
    float rc[3], rs[3];
    rc[0] = 145.801f * cosf(PI - 2.124f); rs[0] = 145.801f * sinf(PI - 2.124f);
    rc[1] = 152.326f * cosf(PI - 1.941f); rs[1] = 152.326f * sinf(PI - 1.941f);
    rc[2] = 132.868f * cosf(PI - 2.028f); rs[2] = 132.868f * sinf(PI - 2.028f);
    const int d0 = b % 3, d1 = (b + 2) % 3, d2 = (b + 1) % 3;
    rcl[0] = rc[d0]; rcl[1] = rc[d1]; rcl[2] = rc[d2];
    rsl[0] = rs[d0]; rsl[1] = rs[d1]; rsl[2] = rs[d2];
}

// R20: TWO-KERNEL SPLIT — deletes the inter-block protocol entirely.
// Ten rounds of structural attacks left exactly one un-falsified hypothesis:
// the one-pass lookback protocol class (agent-scope/multi-XCD semantics:
// L2-bypassing T traffic, wbl2/inv fences, block skew at the spin). Both
// measured wins (relaxed spin -8us, T-dedup -2us) trimmed this class.
// Kernel A writes per-fragment inclusive prefixes P[f][b][12] with PLAIN
// stores; kernel B reads them with PLAIN cached loads. Stream order at the
// kernel boundary provides device-scope (cross-XCD) visibility — no flags,
// no atomics, no fences, no spins. B re-derives local points by re-walking
// the chain from the G-transformed init triple (rigid-motion equivariance;
// refcheck-passed R4 and R10). Known added costs ~7-9us (2nd chain pass +
// dih reload ~5, P traffic ~2, extra dispatch ~2) vs unknown protocol cost.

// ---- Kernel A: frames. Chain (no point storage) -> scan1 -> P rows. ----
__global__ void __launch_bounds__(GROUP * BTILE) frames_kernel(
    const float* __restrict__ dih, float* __restrict__ P)
{
    const int btile = blockIdx.x & (NTILE - 1);
    const int g     = blockIdx.x >> 4;                 // NTILE==16
    const int bsub  = threadIdx.x & (BTILE - 1);
    const int j     = threadIdx.x >> 5;                // BTILE==32
    const int f     = g * GROUP + j;
    const int b     = btile * BTILE + bsub;

    __shared__ float S[GROUP * BTILE * 13];            // stride 13: conflict-free
    float* Srow = &S[(size_t)threadIdx.x * 13];

    float rcl[3], rsl[3];
    lane_consts(b, rcl, rsl);

    float ax = -0.70710678118654752f, ay = 1.22474487139158905f, az = 0.0f;
    float bx = -1.41421356237309505f, by = 0.0f, bz = 0.0f;
    float cx = 0.0f, cy = 0.0f, cz = 0.0f;

    #pragma unroll
    for (int r = 0; r < RPF; ++r) {
        const float* src = dih + (size_t)(f * RPF + r) * (3 * BATCH) + b;
        float dd[3];
        dd[0] = src[0];
        dd[1] = src[BATCH];
        dd[2] = src[2 * BATCH];
        #pragma unroll
        for (int k = 0; k < 3; ++k) {
            float sn, cs;
            __sincosf(dd[k], &sn, &cs);
            float ox, oy, oz;
            nerf_step(ax, ay, az, bx, by, bz, cx, cy, cz,
                      rcl[k], cs * rsl[k], sn * rsl[k], ox, oy, oz);
            ax = bx; ay = by; az = bz;
            bx = cx; by = cy; bz = cz;
            cx = ox; cy = oy; cz = oz;
        }
    }

    {
        float h[12];
        frame_of(ax, ay, az, bx, by, bz, cx, cy, cz, h);
        #pragma unroll
        for (int k = 0; k < 12; ++k) Srow[k] = h[k];
    }
    __syncthreads();

    // In-block Hillis-Steele inclusive scan over j (non-commutative)
    float tmp[12];
    #pragma unroll
    for (int o = 1; o < GROUP; o <<= 1) {
        const bool act = (j >= o);
        if (act) compose(&S[(size_t)(threadIdx.x - o * BTILE) * 13], Srow, tmp);
        __syncthreads();
        if (act) {
            #pragma unroll
            for (int k = 0; k < 12; ++k) Srow[k] = tmp[k];
        }
        __syncthreads();
    }

    // Write this fragment's inclusive prefix row: P[(f*BATCH+b)*12 + k].
    // Row-contiguous 48B per thread -> 3x dwordx4; plain (cached) stores.
    float* dst = P + ((size_t)f * BATCH + b) * 12;
    #pragma unroll
    for (int k = 0; k < 12; ++k) dst[k] = Srow[k];
}

// ---- Kernel B: emit. E_g from P (cached loads) -> G -> chain re-walk. ----
__global__ void __launch_bounds__(GROUP * BTILE) emit_kernel(
    const float* __restrict__ dih, const float* __restrict__ P,
    float* __restrict__ out)
{
    const int btile = blockIdx.x & (NTILE - 1);
    const int g     = blockIdx.x >> 4;                 // NTILE==16
    const int bsub  = threadIdx.x & (BTILE - 1);
    const int j     = threadIdx.x >> 5;                // BTILE==32
    const int f     = g * GROUP + j;
    const int b     = btile * BTILE + bsub;

    __shared__ float Elds[BTILE * 13];                 // E_g broadcast buffer

    float rcl[3], rsl[3];
    lane_consts(b, rcl, rsl);

    const float IAX = -0.70710678118654752f, IAY = 1.22474487139158905f;
    const float IBX = -1.41421356237309505f;

    // Exclusive group prefix E_g = T_0 o ... o T_{g-1}; T_gp is P row
    // gp*GROUP+15. j==0 row computes (32 lanes = this block's b-lanes),
    // LDS broadcast. Plain cached loads — P is L2/IF-hot from kernel A.
    float G[12];
    if (g > 0) {
        if (j == 0) {
            float E[12];
            const float* s0 = P + ((size_t)(GROUP - 1) * BATCH + b) * 12;
            #pragma unroll
            for (int k = 0; k < 12; ++k) E[k] = s0[k];
            #pragma unroll 1
            for (int gp = 1; gp < g; ++gp) {
                const float* sg = P + ((size_t)(gp * GROUP + GROUP - 1) * BATCH + b) * 12;
                float tg[12];
                #pragma unroll
                for (int k = 0; k < 12; ++k) tg[k] = sg[k];
                compose(E, tg, E);
            }
            #pragma unroll
            for (int k = 0; k < 12; ++k) Elds[bsub * 13 + k] = E[k];
        }
        __syncthreads();
        #pragma unroll
        for (int k = 0; k < 12; ++k) G[k] = Elds[bsub * 13 + k];
    } else {
        G[0]=1.f; G[1]=0.f; G[2]=0.f;
        G[3]=0.f; G[4]=1.f; G[5]=0.f;
        G[6]=0.f; G[7]=0.f; G[8]=1.f;
        G[9]=0.f; G[10]=0.f; G[11]=0.f;
    }
    if (j > 0) {
        // P[f-1] = intra-group inclusive prefix of the preceding fragment.
        const float* sp = P + ((size_t)(f - 1) * BATCH + b) * 12;
        float pp[12];
        #pragma unroll
        for (int k = 0; k < 12; ++k) pp[k] = sp[k];
        compose(G, pp, G);
    }

    // Chain re-walk from the G-transformed init triple (equivariance,
    // refcheck-passed R4/R10): every emitted point is global; store direct.
    float ax = G[0]*IAX + G[1]*IAY + G[9];
    float ay = G[3]*IAX + G[4]*IAY + G[10];
    float az = G[6]*IAX + G[7]*IAY + G[11];
    float bx = G[0]*IBX + G[9];
    float by = G[3]*IBX + G[10];
    float bz = G[6]*IBX + G[11];
    float cx = G[9], cy = G[10], cz = G[11];

    #pragma unroll 1
    for (int r = 0; r < RPF; ++r) {
        const float* src = dih + (size_t)(f * RPF + r) * (3 * BATCH) + b;
        float d0 = src[0];
        float d1 = src[BATCH];
        float d2 = src[2 * BATCH];
        float* dst = out + (((size_t)f * (3 * RPF) + r * 3) * BATCH + b) * 3;
        float sn, cs, ox, oy, oz;

        __sincosf(d0, &sn, &cs);
        nerf_step(ax, ay, az, bx, by, bz, cx, cy, cz,
                  rcl[0], cs * rsl[0], sn * rsl[0], ox, oy, oz);
        ax = bx; ay = by; az = bz; bx = cx; by = cy; bz = cz;
        cx = ox; cy = oy; cz = oz;
        dst[0] = ox; dst[1] = oy; dst[2] = oz;

        __sincosf(d1, &sn, &cs);
        nerf_step(ax, ay, az, bx, by, bz, cx, cy, cz,
                  rcl[1], cs * rsl[1], sn * rsl[1], ox, oy, oz);
        ax = bx; ay = by; az = bz; bx = cx; by = cy; bz = cz;
        cx = ox; cy = oy; cz = oz;
        dst += 3 * BATCH;
        dst[0] = ox; dst[1] = oy; dst[2] = oz;

        __sincosf(d2, &sn, &cs);
        nerf_step(ax, ay, az, bx, by, bz, cx, cy, cz,
                  rcl[2], cs * rsl[2], sn * rsl[2], ox, oy, oz);
        ax = bx; ay = by; az = bz; bx = cx; by = cy; bz = cz;
        cx = ox; cy = oy; cz = oz;
        dst += 3 * BATCH;
        dst[0] = ox; dst[1] = oy; dst[2] = oz;
    }
}

extern "C" void kernel_launch(void* const* d_in, const int* in_sizes, int n_in,
                              void* d_out, int out_size, void* d_ws, size_t ws_size,
                              hipStream_t stream) {
    const float* dih = (const float*)d_in[0];
    float* out = (float*)d_out;
    float* P = (float*)d_ws;    // FRAGS*BATCH*12 floats = 6.29 MB

    frames_kernel<<<dim3(NGRP * NTILE), dim3(GROUP * BTILE), 0, stream>>>(dih, P);
    emit_kernel<<<dim3(NGRP * NTILE), dim3(GROUP * BTILE), 0, stream>>>(dih, P, out);
    (void)ws_size; (void)n_in; (void)out_size; (void)in_sizes;
}

// Round 12
// 91.686 us; speedup vs baseline: 1.0648x; 1.0194x over previous
//
#include <hip/hip_runtime.h>
#include <math.h>

#define BATCH 512    // post-reshape scan lanes
#define FRAGS 256    // fragments per chain
#define GROUP 16     // fragments per scan group == frags per block
#define NGRP  (FRAGS/GROUP)   // 16 groups
#define BTILE 32     // batch lanes per block
#define NTILE (BATCH/BTILE)   // 16 b-tiles
#define RPF   8      // residues per fragment (L=2048)
#define READY 0x5EADBEEF

// Rigid transform: 12 floats, R row-major r[i*3+j], t=[9..11]. x' = Rx + t.
// compose(A,B): A is the EARLIER prefix, B the later. (Verified R5-R9.)
__device__ __forceinline__ void compose(const float* A, const float* B, float* D) {
    float d[12];
    #pragma unroll
    for (int i = 0; i < 3; ++i) {
        #pragma unroll
        for (int j = 0; j < 3; ++j)
            d[i*3+j] = A[i*3+0]*B[0*3+j] + A[i*3+1]*B[1*3+j] + A[i*3+2]*B[2*3+j];
        d[9+i] = A[i*3+0]*B[9] + A[i*3+1]*B[10] + A[i*3+2]*B[11] + A[9+i];
    }
    #pragma unroll
    for (int k = 0; k < 12; ++k) D[k] = d[k];
}

__device__ __forceinline__ void frame_of(
    float ax, float ay, float az,
    float bx, float by, float bz,
    float cx, float cy, float cz,
    float* out /*12*/)
{
    float bcx = cx - bx, bcy = cy - by, bcz = cz - bz;
    float inv = rsqrtf(bcx*bcx + bcy*bcy + bcz*bcz + 1e-12f);
    bcx *= inv; bcy *= inv; bcz *= inv;
    float bax = bx - ax, bay = by - ay, baz = bz - az;
    float nx = bay*bcz - baz*bcy;
    float ny = baz*bcx - bax*bcz;
    float nz = bax*bcy - bay*bcx;
    inv = rsqrtf(nx*nx + ny*ny + nz*nz + 1e-12f);
    nx *= inv; ny *= inv; nz *= inv;
    float mx = ny*bcz - nz*bcy;
    float my = nz*bcx - nx*bcz;
    float mz = nx*bcy - ny*bcx;
    out[0] = bcx; out[1] = mx; out[2] = nx;
    out[3] = bcy; out[4] = my; out[5] = ny;
    out[6] = bcz; out[7] = mz; out[8] = nz;
    out[9] = cx; out[10] = cy; out[11] = cz;
}

__device__ __forceinline__ void nerf_step(
    float ax, float ay, float az,
    float bx, float by, float bz,
    float cx, float cy, float cz,
    float px, float py, float pz,
    float& ox, float& oy, float& oz)
{
    float bcx = cx - bx, bcy = cy - by, bcz = cz - bz;
    float inv = rsqrtf(bcx*bcx + bcy*bcy + bcz*bcz + 1e-12f);
    bcx *= inv; bcy *= inv; bcz *= inv;
    float bax = bx - ax, bay = by - ay, baz = bz - az;
    float nx = bay*bcz - baz*bcy;
    float ny = baz*bcx - bax*bcz;
    float nz = bax*bcy - bay*bcx;
    inv = rsqrtf(nx*nx + ny*ny + nz*nz + 1e-12f);
    nx *= inv; ny *= inv; nz *= inv;
    float mx = ny*bcz - nz*bcy;
    float my = nz*bcx - nx*bcz;
    float mz = nx*bcy - ny*bcx;
    ox = bcx*px + mx*py + nx*pz + cx;
    oy = bcy*px + my*py + ny*pz + cy;
    oz = bcz*px + mz*py + nz*pz + cz;
}

// Per-lane permuted bond constants. Reshape (L,B,3,3)->(3L,B,3) makes scan
// lane b at residue l, step k consume dih flat[l*1536 + 512k + b]; bond-const
// index = (512k+b)%3 -> pattern d = {b%3, (b+2)%3, (b+1)%3}. (Verified R5.)
__device__ __forceinline__ void lane_consts(int b, float* rcl, float* rsl) {
    const float PI = 3.14159265358979323846f;
    float rc[3], rs[3];
    rc[0] = 145.801f * cosf(PI - 2.124f); rs[0] = 145.801f * sinf(PI - 2.124f);
    rc[1] = 152.326f * cosf(PI - 1.941f); rs[1] = 152.326f * sinf(PI - 1.941f);
    rc[2] = 132.868f * cosf(PI - 2.028f); rs[2] = 132.868f * sinf(PI - 2.028f);
    const int d0 = b % 3, d1 = (b + 2) % 3, d2 = (b + 1) % 3;
    rcl[0] = rc[d0]; rcl[1] = rc[d1]; rcl[2] = rc[d2];
    rsl[0] = rs[d0]; rsl[1] = rs[d1]; rsl[2] = rs[d2];
}

// FINAL (R21 = R18 restored verbatim — best measured artifact, 92.77us).
// Single-dispatch grid scan via flag lookback. Block = (g, btile): GROUP
// frags x BTILE b-lanes. All 256 blocks co-resident (1/CU) -> spin-wait
// cannot deadlock. Flags poisoned 0xAA pre-launch (!= READY) self-reset.
//
// Session ledger (R0-R11), for posterity:
//  WINS: relaxed spin + one acquire fence (-8us; acquire-spin emits
//        cache-inv + vmcnt-drain per iteration -> device-wide storm);
//        j==0-only E_g + LDS broadcast (-2us; 16x less agent-scope traffic).
//  NULLS/NEGATIVES: spill elimination (R4), occupancy/geometry x2 (R2/R6),
//        intra-thread ILP=2 (R7), code-size/I$ looping (R10), full protocol
//        deletion via two-kernel split (R11) — kernel time invariant at
//        44-49us across all of them. Counters at that point: VALUBusy ~16%,
//        HBM ~11%, LDS conflicts 0, occupancy ~17%. Identifiable critical
//        path ~14us; residual ~34us is per-dispatch, structure-invariant,
//        and not attributable within the available PMC set. Total floor =
//        ~45us harness workspace-poison fill (fixed) + this kernel.
__global__ void __launch_bounds__(GROUP * BTILE) coord_onepass(
    const float* __restrict__ dih, float* __restrict__ T,
    int* __restrict__ flags, float* __restrict__ out)
{
    const int btile = blockIdx.x & (NTILE - 1);
    const int g     = blockIdx.x >> 4;                 // NTILE==16
    const int bsub  = threadIdx.x & (BTILE - 1);
    const int j     = threadIdx.x >> 5;                // BTILE==32
    const int f     = g * GROUP + j;
    const int b     = btile * BTILE + bsub;

    __shared__ float S[GROUP * BTILE * 13];            // stride 13: conflict-free
    __shared__ float Elds[BTILE * 13];                 // E_g broadcast buffer
    float* Srow = &S[(size_t)threadIdx.x * 13];

    float rcl[3], rsl[3];
    lane_consts(b, rcl, rsl);

    // ---- Stage 1: local chain, points kept in registers ----
    float lx[3 * RPF], ly[3 * RPF], lz[3 * RPF];

    float ax = -0.70710678118654752f, ay = 1.22474487139158905f, az = 0.0f;
    float bx = -1.41421356237309505f, by = 0.0f, bz = 0.0f;
    float cx = 0.0f, cy = 0.0f, cz = 0.0f;

    #pragma unroll
    for (int r = 0; r < RPF; ++r) {
        int l = f * RPF + r;
        const float* src = dih + (size_t)l * (3 * BATCH) + b;
        float dd[3];
        dd[0] = src[0];
        dd[1] = src[BATCH];
        dd[2] = src[2 * BATCH];
        #pragma unroll
        for (int k = 0; k < 3; ++k) {
            float sn, cs;
            __sincosf(dd[k], &sn, &cs);
            float ox, oy, oz;
            nerf_step(ax, ay, az, bx, by, bz, cx, cy, cz,
                      rcl[k], cs * rsl[k], sn * rsl[k], ox, oy, oz);
            ax = bx; ay = by; az = bz;
            bx = cx; by = cy; bz = cz;
            cx = ox; cy = oy; cz = oz;
            lx[r * 3 + k] = ox; ly[r * 3 + k] = oy; lz[r * 3 + k] = oz;
        }
    }

    {
        float h[12];
        frame_of(ax, ay, az, bx, by, bz, cx, cy, cz, h);
        #pragma unroll
        for (int k = 0; k < 12; ++k) Srow[k] = h[k];
    }
    __syncthreads();

    // ---- In-block Hillis-Steele inclusive scan over j (non-commutative) ----
    float tmp[12];
    #pragma unroll
    for (int o = 1; o < GROUP; o <<= 1) {
        const bool act = (j >= o);
        if (act) compose(&S[(size_t)(threadIdx.x - o * BTILE) * 13], Srow, tmp);
        __syncthreads();
        if (act) {
            #pragma unroll
            for (int k = 0; k < 12; ++k) Srow[k] = tmp[k];
        }
        __syncthreads();
    }

    // ---- Publish group total T_g (j==GROUP-1 rows), then release flag ----
    if (j == GROUP - 1) {
        #pragma unroll
        for (int k = 0; k < 12; ++k)
            __hip_atomic_store(&T[((size_t)g * 12 + k) * BATCH + b], Srow[k],
                               __ATOMIC_RELAXED, __HIP_MEMORY_SCOPE_AGENT);
    }
    __syncthreads();
    if (threadIdx.x == 0)
        __hip_atomic_store(&flags[g * NTILE + btile], READY,
                           __ATOMIC_RELEASE, __HIP_MEMORY_SCOPE_AGENT);

    // ---- Lookback: spinners are lanes 0..g-1 of wave 0 (relaxed spin, one
    //      acquire fence). Then ONLY row j==0 (same wave; lockstep orders
    //      spin->loads) computes E_g and broadcasts through LDS. ----
    float G[12];
    if (g > 0) {
        if ((int)threadIdx.x < g) {
            while (__hip_atomic_load(&flags[threadIdx.x * NTILE + btile],
                                     __ATOMIC_RELAXED, __HIP_MEMORY_SCOPE_AGENT)
                   != READY) {
                __builtin_amdgcn_s_sleep(1);
            }
        }
        if (j == 0) {
            __builtin_amdgcn_fence(__ATOMIC_ACQUIRE, "agent");
            float E[12];
            #pragma unroll
            for (int k = 0; k < 12; ++k)
                E[k] = __hip_atomic_load(&T[(size_t)k * BATCH + b],
                                         __ATOMIC_RELAXED, __HIP_MEMORY_SCOPE_AGENT);
            for (int gp = 1; gp < g; ++gp) {
                float tg[12];
                #pragma unroll
                for (int k = 0; k < 12; ++k)
                    tg[k] = __hip_atomic_load(&T[((size_t)gp * 12 + k) * BATCH + b],
                                              __ATOMIC_RELAXED, __HIP_MEMORY_SCOPE_AGENT);
                compose(E, tg, E);
            }
            #pragma unroll
            for (int k = 0; k < 12; ++k) Elds[bsub * 13 + k] = E[k];
        }
        __syncthreads();
        #pragma unroll
        for (int k = 0; k < 12; ++k) G[k] = Elds[bsub * 13 + k];
    } else {
        G[0]=1.f; G[1]=0.f; G[2]=0.f;
        G[3]=0.f; G[4]=1.f; G[5]=0.f;
        G[6]=0.f; G[7]=0.f; G[8]=1.f;
        G[9]=0.f; G[10]=0.f; G[11]=0.f;
    }
    if (j > 0) {
        // P[f-1] == inclusive prefix row of thread (j-1, bsub), still in LDS.
        compose(G, &S[(size_t)(threadIdx.x - BTILE) * 13], G);
    }

    // ---- Transform register-held points, coalesced stores ----
    #pragma unroll
    for (int q = 0; q < 3 * RPF; ++q) {
        float ox = lx[q], oy = ly[q], oz = lz[q];
        float gx = G[0]*ox + G[1]*oy + G[2]*oz + G[9];
        float gy = G[3]*ox + G[4]*oy + G[5]*oz + G[10];
        float gz = G[6]*ox + G[7]*oy + G[8]*oz + G[11];
        size_t n = (size_t)f * (3 * RPF) + q;            // scan step index
        float* dst = out + (n * BATCH + b) * 3;
        dst[0] = gx; dst[1] = gy; dst[2] = gz;
    }
}

extern "C" void kernel_launch(void* const* d_in, const int* in_sizes, int n_in,
                              void* d_out, int out_size, void* d_ws, size_t ws_size,
                              hipStream_t stream) {
    const float* dih = (const float*)d_in[0];
    float* out = (float*)d_out;
    float* T = (float*)d_ws;                           // NGRP*12*BATCH floats
    int* flags = (int*)(T + (size_t)NGRP * 12 * BATCH); // NGRP*NTILE ints

    coord_onepass<<<dim3(NGRP * NTILE), dim3(GROUP * BTILE), 0, stream>>>(
        dih, T, flags, out);
    (void)ws_size; (void)n_in; (void)out_size; (void)in_sizes;
}